// Round 5
// baseline (1298.712 us; speedup 1.0000x reference)
//
#include <hip/hip_runtime.h>
#include <math.h>

#define NB 512
#define NNODE 22
#define HH 128
#define NEDGE 462
#define NLAYER 4
#define CHUNK2 128
#define NSUP 4
#define SIG 0.168f

#define ASTR 136      // A-plane row stride (ushort), 272B
#define NSTR 264      // A-plane row stride for node concat (K=256), 528B
#define BSTR 72       // B-plane row stride (ushort), 144B
#define SLW (128*72)  // one weight plane in ushorts (= 9216; 18432 B)
#define LSLICES 14    // slices/layer: ew1:0-3, ew2:4-5, cw1:6-7, nw1:8-11, nw2:12-13
#define STAGE_BYTES 36864

typedef __attribute__((ext_vector_type(8))) short short8;
typedef __attribute__((ext_vector_type(4))) float f32x4;

#define MFMA_BF16 __builtin_amdgcn_mfma_f32_16x16x32_bf16

__device__ __forceinline__ float siluf(float v) { return v / (1.0f + __expf(-v)); }

__device__ __forceinline__ unsigned short f2bf(float x) {
  union { float f; unsigned u; } v; v.f = x;
  unsigned r = v.u + 0x7FFFu + ((v.u >> 16) & 1u);
  return (unsigned short)(r >> 16);
}
__device__ __forceinline__ float bf2f(unsigned short h) {
  union { unsigned u; float f; } v; v.u = ((unsigned)h) << 16; return v.f;
}
// truncation split: hi = truncate(x), lo = round(x - hi)
__device__ __forceinline__ void splitbf(float x, unsigned short& hi, unsigned short& lo) {
  union { float f; unsigned u; } v; v.f = x;
  hi = (unsigned short)(v.u >> 16);
  union { unsigned u; float f; } hv; hv.u = ((unsigned)hi) << 16;
  lo = f2bf(x - hv.f);
}

// ---------------- prep: fp32 weights -> (hi,lo) bf16 planes, transposed [n][k] ----------------
__global__ void prep_weights(const float* __restrict__ ew1, const float* __restrict__ ew2,
                             const float* __restrict__ cw1, const float* __restrict__ nw1,
                             const float* __restrict__ nw2, unsigned short* __restrict__ ws)
{
  int idx = blockIdx.x * 256 + threadIdx.x;      // total = 4*14*128*72 = 516096
  if (idx >= 4 * LSLICES * 128 * 72) return;
  int kk = idx % 72; int rest = idx / 72;
  int n = rest % 128; rest /= 128;
  int sl = rest % LSLICES; int l = rest / LSLICES;
  float val = 0.f;
  if (kk < 64) {
    if (sl < 4)       val = ew1[((size_t)l * 259 + sl * 64 + kk) * HH + n];
    else if (sl < 6)  val = ew2[((size_t)l * 128 + (sl - 4) * 64 + kk) * HH + n];
    else if (sl < 8)  val = cw1[((size_t)l * 128 + (sl - 6) * 64 + kk) * HH + n];
    else if (sl < 12) val = nw1[((size_t)l * 256 + (sl - 8) * 64 + kk) * HH + n];
    else              val = nw2[((size_t)l * 128 + (sl - 12) * 64 + kk) * HH + n];
  }
  unsigned short hi, lo; splitbf(val, hi, lo);
  size_t base = ((size_t)(l * LSLICES + sl) * 2) * SLW + n * BSTR + kk;
  ws[base]       = hi;
  ws[base + SLW] = lo;
}

// ---------------- main ----------------
__global__ __launch_bounds__(512, 1)
void scorenet_kernel(
    const float* __restrict__ xt, const float* __restrict__ tt,
    const float* __restrict__ atom_table, const float* __restrict__ bond_mask,
    const float* __restrict__ W_in, const float* __restrict__ b_in,
    const float* __restrict__ ew1, const float* __restrict__ eb1,
    const float* __restrict__ eb2,
    const float* __restrict__ aw,  const float* __restrict__ ab,
    const float* __restrict__ cb1, const float* __restrict__ cw2,
    const float* __restrict__ nb1, const float* __restrict__ nb2,
    const int* __restrict__ atom_types,
    const unsigned short* __restrict__ ws,
    float* __restrict__ out)
{
  const int g    = blockIdx.x;
  const int tid  = threadIdx.x;
  const int lane = tid & 63;
  const int wv   = tid >> 6;          // 0..7
  const int ml   = lane & 15;
  const int q    = lane >> 4;
  const int grp  = wv >> 2;           // edge sub-chunk group (0/1)
  const int ws4  = wv & 3;            // M-tile within sub-chunk
  const int mtn  = wv & 1;            // Phi/node M-tile
  const int nqn  = wv >> 1;           // Phi/node N-quarter (0..3)

  __shared__ unsigned short sh_B[2 * SLW];           // 36864 B
  __shared__ unsigned short sh_Ah[CHUNK2 * ASTR];    // 34816 B
  __shared__ unsigned short sh_Al[CHUNK2 * ASTR];    // 34816 B
  __shared__ float sh_Phi[2][NNODE * HH];            // 22528 B
  __shared__ float sh_h[NNODE * HH];                 // 11264 B
  __shared__ float sh_agg[NNODE * HH];               // 11264 B
  __shared__ float sh_tail[8 * HH];                  // 4096 B
  __shared__ float sh_awl[HH], sh_cw2l[HH];          // 1024 B
  __shared__ float sh_x[NNODE][3], sh_xacc[NNODE][3];
  __shared__ float sh_d0[NEDGE];                     // fp32: precision-critical
  __shared__ unsigned short sh_bond[NEDGE];          // 0/1 exact in bf16
  __shared__ unsigned char sh_ei[NEDGE], sh_ej[NEDGE];  // node-index LUT
  __shared__ float sh_cd[3][CHUNK2];
  __shared__ float sh_tf[32], sh_scal[2], sh_mean[3];

  // bare staging issue (no barriers): caller's surrounding barriers sequence it
  auto issueB = [&](const unsigned short* src) {
    const char* s8 = (const char*)src;
    char* dbase = (char*)&sh_B[0];
    for (int base = wv * 1024; base < STAGE_BYTES; base += 8192) {
      __builtin_amdgcn_global_load_lds(
          (const __attribute__((address_space(1))) unsigned int*)(s8 + base + lane * 16),
          (__attribute__((address_space(3))) unsigned int*)(dbase + base),
          16, 0, 0);
    }
  };

  auto gemmE = [&](f32x4 (&acc)[8], int koff) {
    int arow = (grp * 64 + ws4 * 16 + ml) * ASTR + koff;
#pragma unroll
    for (int sb = 0; sb < 2; sb++) {
      int ak = arow + sb * 32 + q * 8;
      short8 ah = *(const short8*)&sh_Ah[ak];
      short8 al = *(const short8*)&sh_Al[ak];
#pragma unroll
      for (int t = 0; t < 8; t++) {
        int bi = (t * 16 + ml) * BSTR + sb * 32 + q * 8;
        short8 bh = *(const short8*)&sh_B[bi];
        short8 bl = *(const short8*)&sh_B[SLW + bi];
        acc[t] = MFMA_BF16(ah, bh, acc[t], 0, 0, 0);
        acc[t] = MFMA_BF16(ah, bl, acc[t], 0, 0, 0);
        acc[t] = MFMA_BF16(al, bh, acc[t], 0, 0, 0);
      }
    }
  };

  auto gemmN = [&](f32x4 (&acc)[2], int astr, int koff) {
#pragma unroll
    for (int sb = 0; sb < 2; sb++) {
      int ak = (mtn * 16 + ml) * astr + koff + sb * 32 + q * 8;
      short8 ah = *(const short8*)&sh_Ah[ak];
      short8 al = *(const short8*)&sh_Al[ak];
#pragma unroll
      for (int tt = 0; tt < 2; tt++) {
        int bi = ((nqn * 2 + tt) * 16 + ml) * BSTR + sb * 32 + q * 8;
        short8 bh = *(const short8*)&sh_B[bi];
        short8 bl = *(const short8*)&sh_B[SLW + bi];
        acc[tt] = MFMA_BF16(ah, bh, acc[tt], 0, 0, 0);
        acc[tt] = MFMA_BF16(ah, bl, acc[tt], 0, 0, 0);
        acc[tt] = MFMA_BF16(al, bh, acc[tt], 0, 0, 0);
      }
    }
  };

  // ---------------- init ----------------
  if (tid == 0) {
    float tg = tt[g];
    sh_scal[0] = rsqrtf(tg * tg + SIG * SIG);
    sh_scal[1] = tg;
  }
  __syncthreads();
  const float c_in = sh_scal[0];
  for (int idx = tid; idx < NNODE * 3; idx += 512) {
    sh_x[idx / 3][idx % 3] = xt[(size_t)g * NNODE * 3 + idx] * c_in;
    sh_xacc[idx / 3][idx % 3] = 0.f;
  }
  if (tid < 32) {
    float u = __logf(sh_scal[1]) * 0.25f;
    int   qq = tid & 15;
    float f = __expf((float)qq * -0.5756462732485115f);
    float a = u * f;
    sh_tf[tid] = (tid < 16) ? __sinf(a) : __cosf(a);
  }
  // zero A planes once (avoid garbage in never-written rows)
  for (int idx = tid; idx < CHUNK2 * ASTR / 2; idx += 512) {
    ((unsigned*)sh_Ah)[idx] = 0u; ((unsigned*)sh_Al)[idx] = 0u;
  }
  __syncthreads();
  // Tvec -> sh_agg row 0, atom-type vecs -> rows 1..4 (scratch)
  for (int o = tid; o < HH; o += 512) {
    float s = b_in[o];
#pragma unroll 8
    for (int k = 0; k < 32; k++) s += sh_tf[k] * W_in[k * HH + o];
    sh_agg[o] = s;
  }
  for (int idx = tid; idx < 4 * HH; idx += 512) {
    int a = idx >> 7, o = idx & 127;
    float s = 0.f;
#pragma unroll 8
    for (int k = 0; k < 32; k++) s += atom_table[a * 32 + k] * W_in[(32 + k) * HH + o];
    sh_agg[(1 + a) * HH + o] = s;
  }
  for (int e = tid; e < NEDGE; e += 512) {
    int i = e / 21; int r = e - i * 21; int jn = r + (r >= i);
    sh_ei[e] = (unsigned char)i;
    sh_ej[e] = (unsigned char)jn;
    float dx = sh_x[i][0] - sh_x[jn][0];
    float dy = sh_x[i][1] - sh_x[jn][1];
    float dz = sh_x[i][2] - sh_x[jn][2];
    sh_d0[e]   = dx * dx + dy * dy + dz * dz;
    sh_bond[e] = f2bf(bond_mask[(size_t)g * NEDGE + e]);
  }
  __syncthreads();
  for (int idx = tid; idx < NNODE * HH; idx += 512) {
    int n = idx >> 7, o = idx & 127;
    int at = atom_types[n];
    sh_h[idx] = sh_agg[o] + sh_agg[(1 + at) * HH + o];
  }
  issueB(ws);                           // layer 0, slice 0 in flight
  __syncthreads();
  for (int idx = tid; idx < NNODE * HH; idx += 512) sh_agg[idx] = 0.f;

  const f32x4 zf = {0.f, 0.f, 0.f, 0.f};

  // ---------------- layers ----------------
  for (int l = 0; l < NLAYER; l++) {
    const unsigned short* wsL = ws + (size_t)l * LSLICES * 2 * SLW;
    const float abl = ab[l];

    // ---- layer-top phase (overlaps slice-0 load): vectors + h -> ASTR planes ----
    for (int idx = tid; idx < 8 * HH; idx += 512) {
      int rsel = idx >> 7, n = idx & 127;
      float v;
      switch (rsel) {
        case 0: v = ew1[((size_t)l * 259 + 256) * HH + n]; break;
        case 1: v = ew1[((size_t)l * 259 + 257) * HH + n]; break;
        case 2: v = ew1[((size_t)l * 259 + 258) * HH + n]; break;
        case 3: v = eb1[l * HH + n]; break;
        case 4: v = eb2[l * HH + n]; break;
        case 5: v = cb1[l * HH + n]; break;
        case 6: v = nb1[l * HH + n]; break;
        default: v = nb2[l * HH + n]; break;
      }
      sh_tail[idx] = v;
    }
    if (tid < HH) sh_awl[tid] = aw[l * HH + tid];
    else if (tid < 2 * HH) sh_cw2l[tid - HH] = cw2[l * HH + (tid - HH)];
    for (int idx = tid; idx < NNODE * 16; idx += 512) {
      int nd = idx >> 4, nb = (idx & 15) * 8;
      const float* hp = &sh_h[nd * HH + nb];
      union { short8 v; unsigned short s[8]; } oh, ol;
#pragma unroll
      for (int jj = 0; jj < 8; jj++) { unsigned short hi, lo; splitbf(hp[jj], hi, lo); oh.s[jj] = hi; ol.s[jj] = lo; }
      *(short8*)&sh_Ah[nd * ASTR + nb] = oh.v;
      *(short8*)&sh_Al[nd * ASTR + nb] = ol.v;
    }
    __syncthreads();                      // drain slice0; tail/A visible

    // ---- Phi GEMMs ----
    for (int side = 0; side < 2; side++) {
      f32x4 accP[2] = {zf, zf};
      for (int s2 = 0; s2 < 2; s2++) {
        gemmN(accP, ASTR, s2 * 64);
        __syncthreads();                  // done reading sh_B
        int st = side * 2 + s2;
        issueB(wsL + (st < 3 ? (st + 1) : 4) * 2 * SLW);
        if (s2 == 0) __syncthreads();     // drain (exposed)
      }
#pragma unroll
      for (int tt = 0; tt < 2; tt++) {
        int col = (nqn * 2 + tt) * 16 + ml;
#pragma unroll
        for (int r = 0; r < 4; r++) {
          int row = mtn * 16 + q * 4 + r;
          if (row < NNODE) sh_Phi[side][row * HH + col] = accP[tt][r];
        }
      }
      __syncthreads();                    // drain next slice + Phi visible
    }

    // ---- edge super-chunks (128 edges each, two 4-wave groups) ----
    for (int sc = 0; sc < NSUP; sc++) {
      const int e0 = sc * CHUNK2;
      // (A) prologue m1 (inline rad, LUT indices)  [covers ew2-s0 load]
      {
        int nb = (tid & 15) * 8, eb_ = tid >> 4;
        for (int j4 = 0; j4 < 4; j4++) {
          int el = eb_ + 32 * j4; int e = e0 + el;
          union { short8 v; unsigned short s[8]; } oh, ol;
          if (e < NEDGE) {
            int i = sh_ei[e], jn = sh_ej[e];
            float dx = sh_x[i][0] - sh_x[jn][0];
            float dy = sh_x[i][1] - sh_x[jn][1];
            float dz = sh_x[i][2] - sh_x[jn][2];
            float rad = dx * dx + dy * dy + dz * dz;
            float d0v = sh_d0[e], bnd = bf2f(sh_bond[e]);
            const float* pi = &sh_Phi[0][i * HH + nb];
            const float* pj = &sh_Phi[1][jn * HH + nb];
#pragma unroll
            for (int jj = 0; jj < 8; jj++) {
              float v = pi[jj] + pj[jj] +
                        rad * sh_tail[nb + jj] + d0v * sh_tail[128 + nb + jj] +
                        bnd * sh_tail[256 + nb + jj] + sh_tail[384 + nb + jj];
              unsigned short hi, lo; splitbf(siluf(v), hi, lo);
              oh.s[jj] = hi; ol.s[jj] = lo;
            }
          } else {
#pragma unroll
            for (int jj = 0; jj < 8; jj++) { oh.s[jj] = 0; ol.s[jj] = 0; }
          }
          *(short8*)&sh_Ah[el * ASTR + nb] = oh.v;
          *(short8*)&sh_Al[el * ASTR + nb] = ol.v;
        }
      }
      __syncthreads();                    // (B) drain + m1 visible
      f32x4 acc2[8];
#pragma unroll
      for (int t = 0; t < 8; t++) acc2[t] = zf;
      gemmE(acc2, 0);                     // (C)
      __syncthreads();                    // (D)
      issueB(wsL + 5 * 2 * SLW);          // (E) ew2-s1
      if (tid < CHUNK2) {                 // (F) geometry [cover]
        int e = e0 + tid;
        if (e < NEDGE) {
          int i = sh_ei[e], jn = sh_ej[e];
          float dx = sh_x[i][0] - sh_x[jn][0];
          float dy = sh_x[i][1] - sh_x[jn][1];
          float dz = sh_x[i][2] - sh_x[jn][2];
          float inv = 1.0f / (sqrtf(dx * dx + dy * dy + dz * dz) + 1.0f);
          sh_cd[0][tid] = dx * inv; sh_cd[1][tid] = dy * inv; sh_cd[2][tid] = dz * inv;
        } else {
          sh_cd[0][tid] = 0.f; sh_cd[1][tid] = 0.f; sh_cd[2][tid] = 0.f;
        }
      }
      __syncthreads();                    // (G) drain
      gemmE(acc2, 64);                    // (H)
      __syncthreads();                    // (I)
      issueB(wsL + 6 * 2 * SLW);          // (J) cw1-s0
      // (K) ew2 epilogue: silu + in-register gate + pre-gated m2 write [cover]
      {
        float gpr[4] = {0.f, 0.f, 0.f, 0.f};
#pragma unroll
        for (int t = 0; t < 8; t++) {
          int col = t * 16 + ml;
          float eb2c = sh_tail[512 + col], awc = sh_awl[col];
#pragma unroll
          for (int r = 0; r < 4; r++) {
            float v = siluf(acc2[t][r] + eb2c);
            acc2[t][r] = v;
            gpr[r] += v * awc;
          }
        }
#pragma unroll
        for (int m = 1; m < 16; m <<= 1)
#pragma unroll
          for (int r = 0; r < 4; r++) gpr[r] += __shfl_xor(gpr[r], m, 64);
        float gate[4];
#pragma unroll
        for (int r = 0; r < 4; r++) gate[r] = 1.0f / (1.0f + __expf(-(gpr[r] + abl)));
#pragma unroll
        for (int t = 0; t < 8; t++) {
          int col = t * 16 + ml;
#pragma unroll
          for (int r = 0; r < 4; r++) {
            float vg = acc2[t][r] * gate[r];
            acc2[t][r] = vg;              // keep gated value for deferred agg atomics
            unsigned short hi, lo; splitbf(vg, hi, lo);
            int ai = (grp * 64 + ws4 * 16 + q * 4 + r) * ASTR + col;
            sh_Ah[ai] = hi; sh_Al[ai] = lo;
          }
        }
      }
      __syncthreads();                    // (L) drain + m2 visible
      f32x4 acc3[8];
#pragma unroll
      for (int t = 0; t < 8; t++) acc3[t] = zf;
      gemmE(acc3, 0);                     // (M)
      __syncthreads();                    // (N)
      issueB(wsL + 7 * 2 * SLW);          // (O) cw1-s1
      // (P) deferred agg atomics from registers [cover]
      {
        int nodes[4]; bool emask[4];
#pragma unroll
        for (int r = 0; r < 4; r++) {
          int e = e0 + grp * 64 + ws4 * 16 + q * 4 + r;
          emask[r] = (e < NEDGE);
          nodes[r] = emask[r] ? (int)sh_ei[e] : 0;
        }
#pragma unroll
        for (int t = 0; t < 8; t++) {
          int col = t * 16 + ml;
#pragma unroll
          for (int r = 0; r < 4; r++)
            if (emask[r]) atomicAdd(&sh_agg[nodes[r] * HH + col], acc2[t][r]);
        }
      }
      __syncthreads();                    // (P') drain cw1-s1
      gemmE(acc3, 64);                    // (Q)
      __syncthreads();                    // (R)
      issueB(sc < 3 ? wsL + 4 * 2 * SLW : wsL + 8 * 2 * SLW);  // (S)
      // (T) cw1 epilogue: cs reduce + xacc atomics [cover]
      {
        float cs[4] = {0.f, 0.f, 0.f, 0.f};
#pragma unroll
        for (int t = 0; t < 8; t++) {
          int col = t * 16 + ml;
          float cb1c = sh_tail[640 + col], cwc = sh_cw2l[col];
#pragma unroll
          for (int r = 0; r < 4; r++) cs[r] += siluf(acc3[t][r] + cb1c) * cwc;
        }
#pragma unroll
        for (int m = 1; m < 16; m <<= 1)
#pragma unroll
          for (int r = 0; r < 4; r++) cs[r] += __shfl_xor(cs[r], m, 64);
        if (ml < 3) {
#pragma unroll
          for (int r = 0; r < 4; r++) {
            int le = grp * 64 + ws4 * 16 + q * 4 + r;
            int e = e0 + le;
            if (e < NEDGE)
              atomicAdd(&sh_xacc[sh_ei[e]][ml], sh_cd[ml][le] * cs[r]);
          }
        }
      }
      // no trailing barrier: next prologue (A) touches disjoint LDS; (B) syncs
    } // super-chunks

    // ---- node MLP ----
    // (W) [h|agg] -> NSTR planes  [covers nw1-s0]
    for (int idx = tid; idx < NNODE * 32; idx += 512) {
      int nd = idx >> 5, kb = (idx & 31) * 8;
      const float* src = (kb < 128) ? &sh_h[nd * HH + kb] : &sh_agg[nd * HH + (kb - 128)];
      union { short8 v; unsigned short s[8]; } oh, ol;
#pragma unroll
      for (int jj = 0; jj < 8; jj++) { unsigned short hi, lo; splitbf(src[jj], hi, lo); oh.s[jj] = hi; ol.s[jj] = lo; }
      *(short8*)&sh_Ah[nd * NSTR + kb] = oh.v;
      *(short8*)&sh_Al[nd * NSTR + kb] = ol.v;
    }
    __syncthreads();                      // (X) drain + A + agg-atomics visible
    {
      f32x4 n1a[2] = {zf, zf};
      for (int s = 0; s < 4; s++) {
        gemmN(n1a, NSTR, s * 64);
        __syncthreads();
        issueB(wsL + (s < 3 ? (9 + s) : 12) * 2 * SLW);
        if (s < 3) __syncthreads();       // drain (exposed)
      }
      // n1 epilogue -> ASTR rows 0..21 [covers nw2-s0]
#pragma unroll
      for (int tt = 0; tt < 2; tt++) {
        int col = (nqn * 2 + tt) * 16 + ml;
        float nb1c = sh_tail[768 + col];
#pragma unroll
        for (int r = 0; r < 4; r++) {
          int row = mtn * 16 + q * 4 + r;
          if (row < NNODE) {
            unsigned short hi, lo; splitbf(siluf(n1a[tt][r] + nb1c), hi, lo);
            sh_Ah[row * ASTR + col] = hi; sh_Al[row * ASTR + col] = lo;
          }
        }
      }
      __syncthreads();                    // (Y) drain + A visible
      f32x4 n2a[2] = {zf, zf};
      gemmN(n2a, ASTR, 0);
      __syncthreads();
      issueB(wsL + 13 * 2 * SLW);
      // x-update + resets [covers nw2-s1 load]
      for (int idx = tid; idx < NNODE * 3; idx += 512) {
        int n = idx / 3, d = idx % 3;
        sh_x[n][d] += sh_xacc[n][d];
        sh_xacc[n][d] = 0.f;
      }
      for (int idx = tid; idx < NNODE * HH; idx += 512) sh_agg[idx] = 0.f;
      __syncthreads();                    // drain
      gemmN(n2a, ASTR, 64);
      __syncthreads();
      if (l < 3) issueB(ws + (size_t)(l + 1) * LSLICES * 2 * SLW);  // next layer slice 0
      // n2 epilogue: h += [covers]
#pragma unroll
      for (int tt = 0; tt < 2; tt++) {
        int col = (nqn * 2 + tt) * 16 + ml;
        float nb2c = sh_tail[896 + col];
#pragma unroll
        for (int r = 0; r < 4; r++) {
          int row = mtn * 16 + q * 4 + r;
          if (row < NNODE) sh_h[row * HH + col] += n2a[tt][r] + nb2c;
        }
      }
    }
    __syncthreads();                      // layer end: h visible
  } // layers

  // ---------------- epilogue ----------------
  if (tid < 3) {
    float s = 0.f;
    for (int n = 0; n < NNODE; n++) s += sh_x[n][tid];
    sh_mean[tid] = s * (1.0f / NNODE);
  }
  __syncthreads();
  {
    float tg = sh_scal[1];
    float den = tg * tg + SIG * SIG;
    float c_skip = (SIG * SIG) / den;
    float c_out  = tg * SIG * rsqrtf(den);
    for (int idx = tid; idx < NNODE * 3; idx += 512) {
      int n = idx / 3, d = idx % 3;
      out[(size_t)g * NNODE * 3 + idx] =
          xt[(size_t)g * NNODE * 3 + idx] * c_skip + (sh_x[n][d] - sh_mean[d]) * c_out;
    }
  }
}

extern "C" void kernel_launch(void* const* d_in, const int* in_sizes, int n_in,
                              void* d_out, int out_size, void* d_ws, size_t ws_size,
                              hipStream_t stream) {
  const float* xt         = (const float*)d_in[0];
  const float* t          = (const float*)d_in[1];
  const float* atom_table = (const float*)d_in[2];
  const float* bond_mask  = (const float*)d_in[3];
  const float* W_in       = (const float*)d_in[4];
  const float* b_in       = (const float*)d_in[5];
  const float* ew1        = (const float*)d_in[6];
  const float* eb1        = (const float*)d_in[7];
  const float* ew2        = (const float*)d_in[8];
  const float* eb2        = (const float*)d_in[9];
  const float* aw         = (const float*)d_in[10];
  const float* ab         = (const float*)d_in[11];
  const float* cw1        = (const float*)d_in[12];
  const float* cb1        = (const float*)d_in[13];
  const float* cw2        = (const float*)d_in[14];
  const float* nw1        = (const float*)d_in[15];
  const float* nb1        = (const float*)d_in[16];
  const float* nw2        = (const float*)d_in[17];
  const float* nb2        = (const float*)d_in[18];
  const int* atom_types   = (const int*)d_in[21];

  unsigned short* ws = (unsigned short*)d_ws;   // needs 4*14*2*9216*2 = 2,064,384 B

  prep_weights<<<2016, 256, 0, stream>>>(ew1, ew2, cw1, nw1, nw2, ws);

  scorenet_kernel<<<NB, 512, 0, stream>>>(
      xt, t, atom_table, bond_mask, W_in, b_in,
      ew1, eb1, eb2, aw, ab, cb1, cw2, nb1, nb2,
      atom_types, ws, (float*)d_out);
}

// Round 6
// 703.045 us; speedup vs baseline: 1.8473x; 1.8473x over previous
//
#include <hip/hip_runtime.h>
#include <math.h>

#define NB 512
#define NNODE 22
#define HH 128
#define NEDGE 462
#define NLAYER 4
#define CHUNK2 128
#define NSUP 4
#define SIG 0.168f

#define ASTR 136      // A-plane row stride (ushort), 272B
#define NSTR 264      // A-plane row stride for node concat (K=256), 528B
#define BSTR 72       // B-plane row stride (ushort), 144B
#define SLW (128*72)  // one weight plane in ushorts (= 9216; 18432 B)
#define LSLICES 14    // slices/layer: ew1:0-3, ew2:4-5, cw1:6-7, nw1:8-11, nw2:12-13
#define STAGE_BYTES 36864

typedef __attribute__((ext_vector_type(8))) short short8;
typedef __attribute__((ext_vector_type(4))) short short4v;
typedef __attribute__((ext_vector_type(4))) float f32x4;

#define MFMA_BF16 __builtin_amdgcn_mfma_f32_16x16x32_bf16

__device__ __forceinline__ float siluf(float v) { return v / (1.0f + __expf(-v)); }

__device__ __forceinline__ unsigned short f2bf(float x) {
  union { float f; unsigned u; } v; v.f = x;
  unsigned r = v.u + 0x7FFFu + ((v.u >> 16) & 1u);
  return (unsigned short)(r >> 16);
}
__device__ __forceinline__ float bf2f(unsigned short h) {
  union { unsigned u; float f; } v; v.u = ((unsigned)h) << 16; return v.f;
}
// double-truncation split: hi = trunc(x), lo = trunc(x - hi)  (cheap; residual ~2^-16 rel)
__device__ __forceinline__ void splitbf(float x, unsigned short& hi, unsigned short& lo) {
  union { float f; unsigned u; } v; v.f = x;
  hi = (unsigned short)(v.u >> 16);
  union { unsigned u; float f; } hv; hv.u = ((unsigned)hi) << 16;
  union { float f; unsigned u; } w; w.f = x - hv.f;
  lo = (unsigned short)(w.u >> 16);
}

// ---------------- prep: fp32 weights -> (hi,lo) bf16 planes, transposed [n][k] ----------------
__global__ void prep_weights(const float* __restrict__ ew1, const float* __restrict__ ew2,
                             const float* __restrict__ cw1, const float* __restrict__ nw1,
                             const float* __restrict__ nw2, unsigned short* __restrict__ ws)
{
  int idx = blockIdx.x * 256 + threadIdx.x;      // total = 4*14*128*72 = 516096
  if (idx >= 4 * LSLICES * 128 * 72) return;
  int kk = idx % 72; int rest = idx / 72;
  int n = rest % 128; rest /= 128;
  int sl = rest % LSLICES; int l = rest / LSLICES;
  float val = 0.f;
  if (kk < 64) {
    if (sl < 4)       val = ew1[((size_t)l * 259 + sl * 64 + kk) * HH + n];
    else if (sl < 6)  val = ew2[((size_t)l * 128 + (sl - 4) * 64 + kk) * HH + n];
    else if (sl < 8)  val = cw1[((size_t)l * 128 + (sl - 6) * 64 + kk) * HH + n];
    else if (sl < 12) val = nw1[((size_t)l * 256 + (sl - 8) * 64 + kk) * HH + n];
    else              val = nw2[((size_t)l * 128 + (sl - 12) * 64 + kk) * HH + n];
  }
  // rounded lo for weights (one-time cost)
  unsigned short hi, lo;
  { union { float f; unsigned u; } v; v.f = val;
    hi = (unsigned short)(v.u >> 16);
    union { unsigned u; float f; } hv; hv.u = ((unsigned)hi) << 16;
    lo = f2bf(val - hv.f); }
  size_t base = ((size_t)(l * LSLICES + sl) * 2) * SLW + n * BSTR + kk;
  ws[base]       = hi;
  ws[base + SLW] = lo;
}

// ---------------- main ----------------
__global__ __launch_bounds__(512, 1)
void scorenet_kernel(
    const float* __restrict__ xt, const float* __restrict__ tt,
    const float* __restrict__ atom_table, const float* __restrict__ bond_mask,
    const float* __restrict__ W_in, const float* __restrict__ b_in,
    const float* __restrict__ ew1, const float* __restrict__ eb1,
    const float* __restrict__ eb2,
    const float* __restrict__ aw,  const float* __restrict__ ab,
    const float* __restrict__ cb1, const float* __restrict__ cw2,
    const float* __restrict__ nb1, const float* __restrict__ nb2,
    const int* __restrict__ atom_types,
    const unsigned short* __restrict__ ws,
    float* __restrict__ out)
{
  const int g    = blockIdx.x;
  const int tid  = threadIdx.x;
  const int lane = tid & 63;
  const int wv   = tid >> 6;          // 0..7
  const int ml   = lane & 15;
  const int q    = lane >> 4;
  const int mp   = wv >> 1;           // edge M-pair (rows mp*32 .. +32)
  const int nh2  = wv & 1;            // edge N-half (cols nh2*64 .. +64)
  const int mtn  = wv & 1;            // Phi/node M-tile
  const int nqn  = wv >> 1;           // Phi/node N-quarter (0..3)

  __shared__ __align__(16) unsigned short sh_B[2 * SLW];        // 36864 B
  __shared__ __align__(16) unsigned short sh_Ah[CHUNK2 * ASTR]; // 34816 B
  __shared__ __align__(16) unsigned short sh_Al[CHUNK2 * ASTR]; // 34816 B
  __shared__ float sh_Phi[2][NNODE * HH];            // 22528 B
  __shared__ float sh_h[NNODE * HH];                 // 11264 B
  __shared__ float sh_agg[NNODE * HH];               // 11264 B
  __shared__ float sh_tail[8 * HH];                  // 4096 B
  __shared__ float sh_awl[HH], sh_cw2l[HH];          // 1024 B
  __shared__ float sh_x[NNODE][3], sh_xacc[NNODE][3];
  __shared__ float sh_d0[NEDGE];                     // fp32: precision-critical
  __shared__ unsigned char sh_ei[NEDGE];             // node i (bits 0..4) | bond (bit 7)
  __shared__ unsigned char sh_ej[NEDGE];             // node j
  __shared__ float sh_cd[3][CHUNK2];
  __shared__ float sh_red[CHUNK2][2];                // two-stage reduction partials (gate/cs)
  __shared__ float sh_gate[CHUNK2];
  __shared__ float sh_tf[32], sh_scal[2], sh_mean[3];

  // bare staging issue (no barriers): surrounding barriers sequence it
  auto issueB = [&](const unsigned short* src) {
    const char* s8 = (const char*)src;
    char* dbase = (char*)&sh_B[0];
    for (int base = wv * 1024; base < STAGE_BYTES; base += 8192) {
      __builtin_amdgcn_global_load_lds(
          (const __attribute__((address_space(1))) unsigned int*)(s8 + base + lane * 16),
          (__attribute__((address_space(3))) unsigned int*)(dbase + base),
          16, 0, 0);
    }
  };

  // edge GEMM: 2 M-tiles x 4 N-tiles per wave; B fragments amortized over both M-tiles
  auto gemmE = [&](f32x4 (&acc)[2][4], int koff) {
    int arow0 = (mp * 32 + ml) * ASTR + koff;
    int arow1 = arow0 + 16 * ASTR;
#pragma unroll
    for (int sb = 0; sb < 2; sb++) {
      int k8 = sb * 32 + q * 8;
      short8 ah0 = *(const short8*)&sh_Ah[arow0 + k8];
      short8 al0 = *(const short8*)&sh_Al[arow0 + k8];
      short8 ah1 = *(const short8*)&sh_Ah[arow1 + k8];
      short8 al1 = *(const short8*)&sh_Al[arow1 + k8];
#pragma unroll
      for (int t = 0; t < 4; t++) {
        int bi = ((nh2 * 4 + t) * 16 + ml) * BSTR + k8;
        short8 bh = *(const short8*)&sh_B[bi];
        short8 bl = *(const short8*)&sh_B[SLW + bi];
        acc[0][t] = MFMA_BF16(ah0, bh, acc[0][t], 0, 0, 0);
        acc[0][t] = MFMA_BF16(ah0, bl, acc[0][t], 0, 0, 0);
        acc[0][t] = MFMA_BF16(al0, bh, acc[0][t], 0, 0, 0);
        acc[1][t] = MFMA_BF16(ah1, bh, acc[1][t], 0, 0, 0);
        acc[1][t] = MFMA_BF16(ah1, bl, acc[1][t], 0, 0, 0);
        acc[1][t] = MFMA_BF16(al1, bh, acc[1][t], 0, 0, 0);
      }
    }
  };

  auto gemmN = [&](f32x4 (&acc)[2], int astr, int koff) {
#pragma unroll
    for (int sb = 0; sb < 2; sb++) {
      int ak = (mtn * 16 + ml) * astr + koff + sb * 32 + q * 8;
      short8 ah = *(const short8*)&sh_Ah[ak];
      short8 al = *(const short8*)&sh_Al[ak];
#pragma unroll
      for (int tt = 0; tt < 2; tt++) {
        int bi = ((nqn * 2 + tt) * 16 + ml) * BSTR + sb * 32 + q * 8;
        short8 bh = *(const short8*)&sh_B[bi];
        short8 bl = *(const short8*)&sh_B[SLW + bi];
        acc[tt] = MFMA_BF16(ah, bh, acc[tt], 0, 0, 0);
        acc[tt] = MFMA_BF16(ah, bl, acc[tt], 0, 0, 0);
        acc[tt] = MFMA_BF16(al, bh, acc[tt], 0, 0, 0);
      }
    }
  };

  // ---------------- init ----------------
  if (tid == 0) {
    float tg = tt[g];
    sh_scal[0] = rsqrtf(tg * tg + SIG * SIG);
    sh_scal[1] = tg;
  }
  __syncthreads();
  const float c_in = sh_scal[0];
  for (int idx = tid; idx < NNODE * 3; idx += 512) {
    sh_x[idx / 3][idx % 3] = xt[(size_t)g * NNODE * 3 + idx] * c_in;
    sh_xacc[idx / 3][idx % 3] = 0.f;
  }
  if (tid < 32) {
    float u = __logf(sh_scal[1]) * 0.25f;
    int   qq = tid & 15;
    float f = __expf((float)qq * -0.5756462732485115f);
    float a = u * f;
    sh_tf[tid] = (tid < 16) ? __sinf(a) : __cosf(a);
  }
  for (int idx = tid; idx < CHUNK2 * ASTR / 2; idx += 512) {
    ((unsigned*)sh_Ah)[idx] = 0u; ((unsigned*)sh_Al)[idx] = 0u;
  }
  __syncthreads();
  // Tvec -> sh_agg row 0, atom-type vecs -> rows 1..4 (scratch)
  for (int o = tid; o < HH; o += 512) {
    float s = b_in[o];
#pragma unroll 8
    for (int k = 0; k < 32; k++) s += sh_tf[k] * W_in[k * HH + o];
    sh_agg[o] = s;
  }
  for (int idx = tid; idx < 4 * HH; idx += 512) {
    int a = idx >> 7, o = idx & 127;
    float s = 0.f;
#pragma unroll 8
    for (int k = 0; k < 32; k++) s += atom_table[a * 32 + k] * W_in[(32 + k) * HH + o];
    sh_agg[(1 + a) * HH + o] = s;
  }
  for (int e = tid; e < NEDGE; e += 512) {
    int i = e / 21; int r = e - i * 21; int jn = r + (r >= i);
    float bm = bond_mask[(size_t)g * NEDGE + e];
    sh_ei[e] = (unsigned char)(i | ((bm != 0.f) ? 0x80 : 0));
    sh_ej[e] = (unsigned char)jn;
    float dx = sh_x[i][0] - sh_x[jn][0];
    float dy = sh_x[i][1] - sh_x[jn][1];
    float dz = sh_x[i][2] - sh_x[jn][2];
    sh_d0[e] = dx * dx + dy * dy + dz * dz;
  }
  __syncthreads();
  for (int idx = tid; idx < NNODE * HH; idx += 512) {
    int n = idx >> 7, o = idx & 127;
    int at = atom_types[n];
    sh_h[idx] = sh_agg[o] + sh_agg[(1 + at) * HH + o];
  }
  issueB(ws);                           // layer 0, slice 0 in flight
  __syncthreads();
  for (int idx = tid; idx < NNODE * HH; idx += 512) sh_agg[idx] = 0.f;

  const f32x4 zf = {0.f, 0.f, 0.f, 0.f};

  // ---------------- layers ----------------
  for (int l = 0; l < NLAYER; l++) {
    const unsigned short* wsL = ws + (size_t)l * LSLICES * 2 * SLW;
    const float abl = ab[l];

    // ---- layer-top (covers slice-0 load): per-layer vectors + h -> ASTR planes ----
    for (int idx = tid; idx < 8 * HH; idx += 512) {
      int rsel = idx >> 7, n = idx & 127;
      float v;
      switch (rsel) {
        case 0: v = ew1[((size_t)l * 259 + 256) * HH + n]; break;
        case 1: v = ew1[((size_t)l * 259 + 257) * HH + n]; break;
        case 2: v = ew1[((size_t)l * 259 + 258) * HH + n]; break;
        case 3: v = eb1[l * HH + n]; break;
        case 4: v = eb2[l * HH + n]; break;
        case 5: v = cb1[l * HH + n]; break;
        case 6: v = nb1[l * HH + n]; break;
        default: v = nb2[l * HH + n]; break;
      }
      sh_tail[idx] = v;
    }
    if (tid < HH) sh_awl[tid] = aw[l * HH + tid];
    else if (tid < 2 * HH) sh_cw2l[tid - HH] = cw2[l * HH + (tid - HH)];
    for (int idx = tid; idx < NNODE * 16; idx += 512) {
      int nd = idx >> 4, nb = (idx & 15) * 8;
      const float* hp = &sh_h[nd * HH + nb];
      union { short8 v; unsigned short s[8]; } oh, ol;
#pragma unroll
      for (int jj = 0; jj < 8; jj++) { unsigned short hi, lo; splitbf(hp[jj], hi, lo); oh.s[jj] = hi; ol.s[jj] = lo; }
      *(short8*)&sh_Ah[nd * ASTR + nb] = oh.v;
      *(short8*)&sh_Al[nd * ASTR + nb] = ol.v;
    }
    __syncthreads();                      // drain slice0; tail/A visible

    // ---- Phi GEMMs ----
    for (int side = 0; side < 2; side++) {
      f32x4 accP[2] = {zf, zf};
      for (int s2 = 0; s2 < 2; s2++) {
        gemmN(accP, ASTR, s2 * 64);
        __syncthreads();                  // done reading sh_B
        int st = side * 2 + s2;
        issueB(wsL + (st < 3 ? (st + 1) : 4) * 2 * SLW);
        if (s2 == 0) __syncthreads();     // drain (exposed)
      }
#pragma unroll
      for (int tt = 0; tt < 2; tt++) {
        int col = (nqn * 2 + tt) * 16 + ml;
#pragma unroll
        for (int r = 0; r < 4; r++) {
          int row = mtn * 16 + q * 4 + r;
          if (row < NNODE) sh_Phi[side][row * HH + col] = accP[tt][r];
        }
      }
      __syncthreads();                    // drain next slice + Phi visible
    }

    // ---- edge super-chunks (128 edges, 8 waves as 4 M-pairs x 2 N-halves) ----
    for (int sc = 0; sc < NSUP; sc++) {
      const int e0 = sc * CHUNK2;
      // (A) prologue m1 [covers ew2-s0 load]
      {
        int nb = (tid & 15) * 8, eb_ = tid >> 4;
        for (int j4 = 0; j4 < 4; j4++) {
          int el = eb_ + 32 * j4; int e = e0 + el;
          union { short8 v; unsigned short s[8]; } oh, ol;
          if (e < NEDGE) {
            int c = sh_ei[e]; int i = c & 31; int jn = sh_ej[e];
            float bnd = (float)(c >> 7);
            float dx = sh_x[i][0] - sh_x[jn][0];
            float dy = sh_x[i][1] - sh_x[jn][1];
            float dz = sh_x[i][2] - sh_x[jn][2];
            float rad = dx * dx + dy * dy + dz * dz;
            float d0v = sh_d0[e];
            const float* pi = &sh_Phi[0][i * HH + nb];
            const float* pj = &sh_Phi[1][jn * HH + nb];
#pragma unroll
            for (int jj = 0; jj < 8; jj++) {
              float v = pi[jj] + pj[jj] +
                        rad * sh_tail[nb + jj] + d0v * sh_tail[128 + nb + jj] +
                        bnd * sh_tail[256 + nb + jj] + sh_tail[384 + nb + jj];
              unsigned short hi, lo; splitbf(siluf(v), hi, lo);
              oh.s[jj] = hi; ol.s[jj] = lo;
            }
          } else {
#pragma unroll
            for (int jj = 0; jj < 8; jj++) { oh.s[jj] = 0; ol.s[jj] = 0; }
          }
          *(short8*)&sh_Ah[el * ASTR + nb] = oh.v;
          *(short8*)&sh_Al[el * ASTR + nb] = ol.v;
        }
      }
      __syncthreads();                    // (B) drain ew2-s0 + m1 visible
      f32x4 acc2[2][4];
#pragma unroll
      for (int m2i = 0; m2i < 2; m2i++)
#pragma unroll
        for (int t = 0; t < 4; t++) acc2[m2i][t] = zf;
      gemmE(acc2, 0);                     // (C)
      __syncthreads();                    // (D)
      issueB(wsL + 5 * 2 * SLW);          // (E) ew2-s1
      if (tid < CHUNK2) {                 // (F) geometry [cover]
        int e = e0 + tid;
        if (e < NEDGE) {
          int i = sh_ei[e] & 31, jn = sh_ej[e];
          float dx = sh_x[i][0] - sh_x[jn][0];
          float dy = sh_x[i][1] - sh_x[jn][1];
          float dz = sh_x[i][2] - sh_x[jn][2];
          float inv = 1.0f / (sqrtf(dx * dx + dy * dy + dz * dz) + 1.0f);
          sh_cd[0][tid] = dx * inv; sh_cd[1][tid] = dy * inv; sh_cd[2][tid] = dz * inv;
        } else {
          sh_cd[0][tid] = 0.f; sh_cd[1][tid] = 0.f; sh_cd[2][tid] = 0.f;
        }
      }
      __syncthreads();                    // (G) drain ew2-s1
      gemmE(acc2, 64);                    // (H)
      __syncthreads();                    // (I)
      issueB(wsL + 6 * 2 * SLW);          // (J) cw1-s0
      // (K1) silu, UNGATED m2 write, gate partial sums -> sh_red [cover]
      {
        float gpr[2][4];
#pragma unroll
        for (int m2i = 0; m2i < 2; m2i++)
#pragma unroll
          for (int r = 0; r < 4; r++) gpr[m2i][r] = 0.f;
#pragma unroll
        for (int m2i = 0; m2i < 2; m2i++) {
#pragma unroll
          for (int t = 0; t < 4; t++) {
            int col = nh2 * 64 + t * 16 + ml;
            float eb2c = sh_tail[512 + col], awc = sh_awl[col];
#pragma unroll
            for (int r = 0; r < 4; r++) {
              float v = siluf(acc2[m2i][t][r] + eb2c);
              gpr[m2i][r] += v * awc;
              unsigned short hi, lo; splitbf(v, hi, lo);
              int ai = (mp * 32 + m2i * 16 + q * 4 + r) * ASTR + col;
              sh_Ah[ai] = hi; sh_Al[ai] = lo;
            }
          }
        }
#pragma unroll
        for (int m = 1; m < 16; m <<= 1)
#pragma unroll
          for (int m2i = 0; m2i < 2; m2i++)
#pragma unroll
            for (int r = 0; r < 4; r++) gpr[m2i][r] += __shfl_xor(gpr[m2i][r], m, 64);
        if (ml == 0) {
#pragma unroll
          for (int m2i = 0; m2i < 2; m2i++)
#pragma unroll
            for (int r = 0; r < 4; r++)
              sh_red[mp * 32 + m2i * 16 + q * 4 + r][nh2] = gpr[m2i][r];
        }
      }
      __syncthreads();                    // (K2) drain cw1-s0 + m2/partials visible
      // (M) gate materialize + cw1 GEMM
      if (tid < CHUNK2)
        sh_gate[tid] = 1.0f / (1.0f + __expf(-(sh_red[tid][0] + sh_red[tid][1] + abl)));
      f32x4 acc3[2][4];
#pragma unroll
      for (int m2i = 0; m2i < 2; m2i++)
#pragma unroll
        for (int t = 0; t < 4; t++) acc3[m2i][t] = zf;
      gemmE(acc3, 0);
      __syncthreads();                    // (N)
      issueB(wsL + 7 * 2 * SLW);          // (O) cw1-s1
      // (P) agg += gate[e] * m2[e][:]  (vectorized row-sorted segments) [cover]
      int elast = ((e0 + CHUNK2 < NEDGE) ? e0 + CHUNK2 : NEDGE) - 1;
      int i_lo = e0 / 21, i_hi = elast / 21;
      int nrows = i_hi - i_lo + 1;
      for (int idx = tid; idx < nrows * 32; idx += 512) {
        int i = i_lo + (idx >> 5), fb = (idx & 31) * 4;
        int es = i * 21; if (es < e0) es = e0;
        int ee = i * 21 + 21;
        if (ee > e0 + CHUNK2) ee = e0 + CHUNK2;
        if (ee > NEDGE) ee = NEDGE;
        float* ap = &sh_agg[i * HH + fb];
        float a4[4];
#pragma unroll
        for (int c = 0; c < 4; c++) a4[c] = ap[c];
        for (int e = es; e < ee; e++) {
          float gg = sh_gate[e - e0];
          union { short4v v; unsigned short s[4]; } uh, ul;
          uh.v = *(const short4v*)&sh_Ah[(e - e0) * ASTR + fb];
          ul.v = *(const short4v*)&sh_Al[(e - e0) * ASTR + fb];
#pragma unroll
          for (int c = 0; c < 4; c++) a4[c] += gg * (bf2f(uh.s[c]) + bf2f(ul.s[c]));
        }
#pragma unroll
        for (int c = 0; c < 4; c++) ap[c] = a4[c];
      }
      __syncthreads();                    // (Pb) drain cw1-s1
      gemmE(acc3, 64);                    // (Q)
      __syncthreads();                    // (R)
      issueB(sc < 3 ? wsL + 4 * 2 * SLW : wsL + 8 * 2 * SLW);  // (S)
      // (T) cs partials (gate folded linearly through cw1) -> sh_red [cover]
      {
        float cs[2][4];
#pragma unroll
        for (int m2i = 0; m2i < 2; m2i++) {
          float g4[4];
#pragma unroll
          for (int r = 0; r < 4; r++) {
            g4[r] = sh_gate[mp * 32 + m2i * 16 + q * 4 + r];
            cs[m2i][r] = 0.f;
          }
#pragma unroll
          for (int t = 0; t < 4; t++) {
            int col = nh2 * 64 + t * 16 + ml;
            float cb1c = sh_tail[640 + col], cwc = sh_cw2l[col];
#pragma unroll
            for (int r = 0; r < 4; r++)
              cs[m2i][r] += siluf(g4[r] * acc3[m2i][t][r] + cb1c) * cwc;
          }
        }
#pragma unroll
        for (int m = 1; m < 16; m <<= 1)
#pragma unroll
          for (int m2i = 0; m2i < 2; m2i++)
#pragma unroll
            for (int r = 0; r < 4; r++) cs[m2i][r] += __shfl_xor(cs[m2i][r], m, 64);
        if (ml == 0) {
#pragma unroll
          for (int m2i = 0; m2i < 2; m2i++)
#pragma unroll
            for (int r = 0; r < 4; r++)
              sh_red[mp * 32 + m2i * 16 + q * 4 + r][nh2] = cs[m2i][r];
        }
      }
      __syncthreads();                    // (U) cs partials visible (drains S under T)
      // (V) xacc accumulate (cmul = red0+red1 inline); next prologue may overlap after
      for (int idx = tid; idx < nrows * 3; idx += 512) {
        int i = i_lo + idx / 3, d = idx % 3;
        int es = i * 21; if (es < e0) es = e0;
        int ee = i * 21 + 21;
        if (ee > e0 + CHUNK2) ee = e0 + CHUNK2;
        if (ee > NEDGE) ee = NEDGE;
        float s = 0.f;
        for (int e = es; e < ee; e++)
          s += sh_cd[d][e - e0] * (sh_red[e - e0][0] + sh_red[e - e0][1]);
        sh_xacc[i][d] += s;
      }
      // no trailing barrier: next (A) writes disjoint LDS; (B) orders everything
    } // super-chunks

    // ---- node MLP ----
    // (W) [h|agg] -> NSTR planes [covers nw1-s0]
    for (int idx = tid; idx < NNODE * 32; idx += 512) {
      int nd = idx >> 5, kb = (idx & 31) * 8;
      const float* src = (kb < 128) ? &sh_h[nd * HH + kb] : &sh_agg[nd * HH + (kb - 128)];
      union { short8 v; unsigned short s[8]; } oh, ol;
#pragma unroll
      for (int jj = 0; jj < 8; jj++) { unsigned short hi, lo; splitbf(src[jj], hi, lo); oh.s[jj] = hi; ol.s[jj] = lo; }
      *(short8*)&sh_Ah[nd * NSTR + kb] = oh.v;
      *(short8*)&sh_Al[nd * NSTR + kb] = ol.v;
    }
    __syncthreads();                      // (X) drain + A visible
    {
      f32x4 n1a[2] = {zf, zf};
      for (int s = 0; s < 4; s++) {
        gemmN(n1a, NSTR, s * 64);
        __syncthreads();
        issueB(wsL + (s < 3 ? (9 + s) : 12) * 2 * SLW);
        if (s < 3) __syncthreads();       // drain (exposed)
      }
      // n1 epilogue -> ASTR rows 0..21 [covers nw2-s0]
#pragma unroll
      for (int tt = 0; tt < 2; tt++) {
        int col = (nqn * 2 + tt) * 16 + ml;
        float nb1c = sh_tail[768 + col];
#pragma unroll
        for (int r = 0; r < 4; r++) {
          int row = mtn * 16 + q * 4 + r;
          if (row < NNODE) {
            unsigned short hi, lo; splitbf(siluf(n1a[tt][r] + nb1c), hi, lo);
            sh_Ah[row * ASTR + col] = hi; sh_Al[row * ASTR + col] = lo;
          }
        }
      }
      __syncthreads();                    // (Y) drain + A visible
      f32x4 n2a[2] = {zf, zf};
      gemmN(n2a, ASTR, 0);
      __syncthreads();
      issueB(wsL + 13 * 2 * SLW);
      // x-update + resets [covers nw2-s1 load]
      for (int idx = tid; idx < NNODE * 3; idx += 512) {
        int n = idx / 3, d = idx % 3;
        sh_x[n][d] += sh_xacc[n][d];
        sh_xacc[n][d] = 0.f;
      }
      for (int idx = tid; idx < NNODE * HH; idx += 512) sh_agg[idx] = 0.f;
      __syncthreads();                    // drain
      gemmN(n2a, ASTR, 64);
      __syncthreads();
      if (l < 3) issueB(ws + (size_t)(l + 1) * LSLICES * 2 * SLW);  // next layer slice 0
      // n2 epilogue: h += [covers]
#pragma unroll
      for (int tt = 0; tt < 2; tt++) {
        int col = (nqn * 2 + tt) * 16 + ml;
        float nb2c = sh_tail[896 + col];
#pragma unroll
        for (int r = 0; r < 4; r++) {
          int row = mtn * 16 + q * 4 + r;
          if (row < NNODE) sh_h[row * HH + col] += n2a[tt][r] + nb2c;
        }
      }
    }
    __syncthreads();                      // layer end: h visible
  } // layers

  // ---------------- epilogue ----------------
  if (tid < 3) {
    float s = 0.f;
    for (int n = 0; n < NNODE; n++) s += sh_x[n][tid];
    sh_mean[tid] = s * (1.0f / NNODE);
  }
  __syncthreads();
  {
    float tg = sh_scal[1];
    float den = tg * tg + SIG * SIG;
    float c_skip = (SIG * SIG) / den;
    float c_out  = tg * SIG * rsqrtf(den);
    for (int idx = tid; idx < NNODE * 3; idx += 512) {
      int n = idx / 3, d = idx % 3;
      out[(size_t)g * NNODE * 3 + idx] =
          xt[(size_t)g * NNODE * 3 + idx] * c_skip + (sh_x[n][d] - sh_mean[d]) * c_out;
    }
  }
}

extern "C" void kernel_launch(void* const* d_in, const int* in_sizes, int n_in,
                              void* d_out, int out_size, void* d_ws, size_t ws_size,
                              hipStream_t stream) {
  const float* xt         = (const float*)d_in[0];
  const float* t          = (const float*)d_in[1];
  const float* atom_table = (const float*)d_in[2];
  const float* bond_mask  = (const float*)d_in[3];
  const float* W_in       = (const float*)d_in[4];
  const float* b_in       = (const float*)d_in[5];
  const float* ew1        = (const float*)d_in[6];
  const float* eb1        = (const float*)d_in[7];
  const float* ew2        = (const float*)d_in[8];
  const float* eb2        = (const float*)d_in[9];
  const float* aw         = (const float*)d_in[10];
  const float* ab         = (const float*)d_in[11];
  const float* cw1        = (const float*)d_in[12];
  const float* cb1        = (const float*)d_in[13];
  const float* cw2        = (const float*)d_in[14];
  const float* nw1        = (const float*)d_in[15];
  const float* nb1        = (const float*)d_in[16];
  const float* nw2        = (const float*)d_in[17];
  const float* nb2        = (const float*)d_in[18];
  const int* atom_types   = (const int*)d_in[21];

  unsigned short* ws = (unsigned short*)d_ws;   // needs 4*14*2*9216*2 = 2,064,384 B

  prep_weights<<<2016, 256, 0, stream>>>(ew1, ew2, cw1, nw1, nw2, ws);

  scorenet_kernel<<<NB, 512, 0, stream>>>(
      xt, t, atom_table, bond_mask, W_in, b_in,
      ew1, eb1, eb2, aw, ab, cb1, cw2, nb1, nb2,
      atom_types, ws, (float*)d_out);
}